// Round 6
// baseline (110.686 us; speedup 1.0000x reference)
//
#include <hip/hip_runtime.h>
#include <math.h>

#define NROWS 8192
#define DIM 512
#define INV_T 20.0f
#define QS 500.0f
// dequant * 1/T * log2(e), for exp2-based softmax accumulation
#define DEQ2 (INV_T * 1.4426950408889634f / (QS * QS))

typedef __attribute__((ext_vector_type(4))) int i32x4;

__device__ __forceinline__ void gload_lds16(const void* g, void* l) {
    __builtin_amdgcn_global_load_lds(
        (const __attribute__((address_space(1))) unsigned int*)g,
        (__attribute__((address_space(3))) unsigned int*)l, 16, 0, 0);
}

__device__ __forceinline__ float dot4(float4 a, float4 b) {
    return a.x * b.x + a.y * b.y + a.z * b.z + a.w * b.w;
}

__device__ __forceinline__ int q4(float4 v, float s) {
    int b0 = __float2int_rn(fminf(fmaxf(v.x * s, -127.f), 127.f)) & 255;
    int b1 = __float2int_rn(fminf(fmaxf(v.y * s, -127.f), 127.f)) & 255;
    int b2 = __float2int_rn(fminf(fmaxf(v.z * s, -127.f), 127.f)) & 255;
    int b3 = __float2int_rn(fminf(fmaxf(v.w * s, -127.f), 127.f)) & 255;
    return b0 | (b1 << 8) | (b2 << 16) | (b3 << 24);
}

// One wave per row: L2-normalize, quantize to i8 (scale QS), exact fp32 diag,
// column log2-weights (0 or 1), zero row-sum accumulator.
__global__ __launch_bounds__(256) void norm_kernel(
    const float* __restrict__ A, const float* __restrict__ S,
    const int* __restrict__ labels, signed char* __restrict__ aQ,
    signed char* __restrict__ sQ, float* __restrict__ diag,
    float* __restrict__ lw2, float* __restrict__ lsum) {
    const int wave = threadIdx.x >> 6, lane = threadIdx.x & 63;
    const int row = blockIdx.x * 4 + wave;
    const float4* a4 = (const float4*)(A + (size_t)row * DIM);
    const float4* s4 = (const float4*)(S + (size_t)row * DIM);
    float4 a0 = a4[lane], a1 = a4[lane + 64];
    float4 s0 = s4[lane], s1 = s4[lane + 64];
    float saa = dot4(a0, a0) + dot4(a1, a1);
    float sss = dot4(s0, s0) + dot4(s1, s1);
    float sas = dot4(a0, s0) + dot4(a1, s1);
    for (int m = 1; m < 64; m <<= 1) {
        saa += __shfl_xor(saa, m);
        sss += __shfl_xor(sss, m);
        sas += __shfl_xor(sas, m);
    }
    const float ra = rsqrtf(saa), rs = rsqrtf(sss);
    signed char* arow = aQ + (size_t)row * DIM;
    signed char* srow = sQ + (size_t)row * DIM;
    *(int*)(arow + lane * 4)       = q4(a0, ra * QS);
    *(int*)(arow + 256 + lane * 4) = q4(a1, ra * QS);
    *(int*)(srow + lane * 4)       = q4(s0, rs * QS);
    *(int*)(srow + 256 + lane * 4) = q4(s1, rs * QS);
    if (lane == 0) {
        diag[row] = sas * ra * rs * INV_T;
        // Uniform column weighting (incl. diagonal) is exact for the final
        // loss: only label==1 rows' lse is consumed, and those rows' diagonal
        // column has log_w==0 in the reference anyway. log2-weight: 0 or 1.
        lw2[row] = (labels[row] == 0) ? 1.0f : 0.0f;
        lsum[row] = 0.0f;
    }
}

// ---------------------------------------------------------------------------
// Barrier-free fused i8 GEMM + exp2 + row-sum.
// Block = 128 rows x 512 cols (4 ct of 128), 4 waves (2x2).
// A panel 128x512 i8 (64 KB LDS) staged ONCE (r4-verified swizzle); B operand
// fragments loaded DIRECTLY global->VGPR, double-buffered in registers.
// Zero barriers / zero LDS writes in the main loop: each wave is a self-timed
// {4 B-loads + 4 A-ds_reads -> 16 MFMA} stream; register WAR throttles
// lookahead to one window. One barrier total (after A staging, vmcnt(4)).
// ---------------------------------------------------------------------------
#define BM 128

__global__ __launch_bounds__(256) void lse_gemm(
    const signed char* __restrict__ Aq, const signed char* __restrict__ Bq,
    const float* __restrict__ lw2, float* __restrict__ lsum) {
    __shared__ __align__(16) char ldsA[BM * 512];  // 64 KB persistent A panel

    const int bid = blockIdx.x;               // 1024 blocks
    const int rt = bid & 63, ctg = bid >> 6;  // rt-consecutive -> XCD spread
    const int row0 = rt * BM;
    const int colg = ctg * 512;

    const int tid = threadIdx.x;
    const int wave = tid >> 6, lane = tid & 63;
    const int wm = wave >> 1, wn = wave & 1;
    const int fr = lane & 15, grp = lane >> 4;
    const int wbase = wave << 10;  // wave-uniform LDS dest offset

    // ---- A panel staging (r4-verified): 16 rounds x 8 rows. Thread t lands
    // at byte r*4096 + t*16 -> row = r*8 + (t>>5), phys slot = t&31. Fetch
    // logical slot (t&31)^(row&31) so swizzled reads see linear data.
#pragma unroll
    for (int r = 0; r < 16; ++r) {
        const int rowA = r * 8 + (tid >> 5);
        const int l = (tid & 31) ^ (rowA & 31);
        gload_lds16(Aq + (size_t)(row0 + rowA) * DIM + l * 16,
                    ldsA + r * 4096 + wbase);
    }

    // B direct-load base: fragment n of window (ct,k) is 16 B at
    // row (colg + ct*128 + wn*64 + n*16 + fr), bytes k*64 + grp*16.
    const signed char* Bbase =
        Bq + (size_t)(colg + wn * 64 + fr) * DIM + grp * 16;

    i32x4 a[2][4], b[2][4];

    // first B window issued BEFORE the A-stage drain (stays in flight)
#pragma unroll
    for (int n = 0; n < 4; ++n)
        b[0][n] = *(const i32x4*)(Bbase + (size_t)(n * 16) * DIM);

    asm volatile("s_waitcnt vmcnt(4)" ::: "memory");  // A staged; B in flight
    asm volatile("" ::: "memory");
    __builtin_amdgcn_s_barrier();
    asm volatile("" ::: "memory");

    // A fragment reads (swizzled): row wm*64+m*16+fr, phys slot (k*4+grp)^(row&31)
#define LOAD_A(buf, k)                                                        \
    do {                                                                      \
        _Pragma("unroll")                                                     \
        for (int m = 0; m < 4; ++m) {                                         \
            const int rowm = wm * 64 + m * 16 + fr;                           \
            const int ps = (((k) * 4 + grp) ^ (rowm & 31)) << 4;              \
            a[buf][m] = *(const i32x4*)&ldsA[rowm * 512 + ps];                \
        }                                                                     \
    } while (0)

#define LOAD_B(buf, ct, k)                                                    \
    do {                                                                      \
        _Pragma("unroll")                                                     \
        for (int n = 0; n < 4; ++n)                                           \
            b[buf][n] = *(const i32x4*)(Bbase +                               \
                (size_t)((ct) * 128 + n * 16) * DIM + (k) * 64);              \
    } while (0)

    LOAD_A(0, 0);

    float rsum[4][4] = {};  // [m][j] accumulated across all 4 ct

#pragma unroll
    for (int ct = 0; ct < 4; ++ct) {
        i32x4 acc[4][4] = {};
#pragma unroll
        for (int k = 0; k < 8; ++k) {
            const int cur = k & 1, nxt = cur ^ 1;
            if (k < 7) {
                LOAD_B(nxt, ct, k + 1);
                LOAD_A(nxt, k + 1);
            } else if (ct < 3) {
                LOAD_B(nxt, ct + 1, 0);
                LOAD_A(nxt, 0);
            }
#pragma unroll
            for (int m = 0; m < 4; ++m)
#pragma unroll
                for (int n = 0; n < 4; ++n)
                    acc[m][n] = __builtin_amdgcn_mfma_i32_16x16x64_i8(
                        a[cur][m], b[cur][n], acc[m][n], 0, 0, 0);
        }

        // per-ct epilogue: uniform column weights, exp2-folded dequant.
        const int col0 = colg + ct * 128;
        float lwv[4];
#pragma unroll
        for (int n = 0; n < 4; ++n)
            lwv[n] = lw2[col0 + wn * 64 + n * 16 + fr];
#pragma unroll
        for (int m = 0; m < 4; ++m)
#pragma unroll
            for (int n = 0; n < 4; ++n)
#pragma unroll
                for (int j = 0; j < 4; ++j)
                    rsum[m][j] += exp2f(fmaf((float)acc[m][n][j], DEQ2, lwv[n]));
    }
#undef LOAD_A
#undef LOAD_B

    // final: reduce rsum over the 16-lane fr group, one atomicAdd per row
#pragma unroll
    for (int m = 0; m < 4; ++m)
#pragma unroll
        for (int j = 0; j < 4; ++j) {
            float v = rsum[m][j];
            v += __shfl_xor(v, 1);
            v += __shfl_xor(v, 2);
            v += __shfl_xor(v, 4);
            v += __shfl_xor(v, 8);
            if (fr == 0)
                atomicAdd(&lsum[row0 + wm * 64 + m * 16 + grp * 4 + j], v);
        }
}

// 1024 threads, single block: final scalar reduction.
__global__ __launch_bounds__(1024) void finalize_kernel(
    const float* __restrict__ lsum, const float* __restrict__ diag,
    const int* __restrict__ labels, float* __restrict__ out) {
    const int tid = threadIdx.x;
    float sl = 0.f, sd = 0.f, mx = -1e9f;
    int np_ = 0, nn_ = 0;
#pragma unroll
    for (int i = tid; i < NROWS; i += 1024) {
        const float dg = diag[i];
        if (labels[i] == 1) {
            sl += logf(lsum[i]) - dg;
            sd += dg;
            np_++;
        } else {
            nn_++;
            mx = fmaxf(mx, dg);
        }
    }
    for (int m = 1; m < 64; m <<= 1) {
        sl += __shfl_xor(sl, m);
        sd += __shfl_xor(sd, m);
        mx = fmaxf(mx, __shfl_xor(mx, m));
        np_ += __shfl_xor(np_, m);
        nn_ += __shfl_xor(nn_, m);
    }
    __shared__ float rsl[16], rsd[16], rmx[16];
    __shared__ int rnp[16], rnn[16];
    const int wave = tid >> 6, lane = tid & 63;
    if (lane == 0) {
        rsl[wave] = sl; rsd[wave] = sd; rmx[wave] = mx;
        rnp[wave] = np_; rnn[wave] = nn_;
    }
    __syncthreads();
    if (tid == 0) {
        float SL = 0.f, SD = 0.f, MX = -1e9f;
        int NP = 0, NN = 0;
        for (int w = 0; w < 16; w++) {
            SL += rsl[w]; SD += rsd[w]; MX = fmaxf(MX, rmx[w]);
            NP += rnp[w]; NN += rnn[w];
        }
        const float infonce = SL / (float)NP;
        const float meanpos = SD / (float)NP;
        float pen = fmaxf(MX - meanpos + 0.2f, 0.0f);
        if (NN == 0) pen = 0.0f;
        out[0] = infonce + pen;
    }
}

extern "C" void kernel_launch(void* const* d_in, const int* in_sizes, int n_in,
                              void* d_out, int out_size, void* d_ws, size_t ws_size,
                              hipStream_t stream) {
    const float* A = (const float*)d_in[0];
    const float* S = (const float*)d_in[1];
    const int* labels = (const int*)d_in[2];
    float* out = (float*)d_out;

    char* ws = (char*)d_ws;
    signed char* aQ = (signed char*)ws;                          // 4 MB
    signed char* sQ = (signed char*)(ws + (size_t)NROWS * DIM);  // 4 MB
    char* p = ws + (size_t)NROWS * DIM * 2;
    float* diag = (float*)p;                // 32 KB
    float* lw2 = (float*)(p + 32768);       // 32 KB
    float* lsum = (float*)(p + 65536);      // 32 KB

    norm_kernel<<<NROWS / 4, 256, 0, stream>>>(A, S, labels, aQ, sQ, diag, lw2, lsum);
    lse_gemm<<<64 * 16, 256, 0, stream>>>(aQ, sQ, lw2, lsum);
    finalize_kernel<<<1, 1024, 0, stream>>>(lsum, diag, labels, out);
}

// Round 7
// 72.383 us; speedup vs baseline: 1.5292x; 1.5292x over previous
//
#include <hip/hip_runtime.h>
#include <math.h>

#define NROWS 8192
#define DIM 512
#define INV_T 20.0f
#define QS 500.0f
// dequant * 1/T * log2(e), for exp2-based softmax accumulation
#define DEQ2 (INV_T * 1.4426950408889634f / (QS * QS))

typedef __attribute__((ext_vector_type(4))) int i32x4;

__device__ __forceinline__ void gload_lds16(const void* g, void* l) {
    __builtin_amdgcn_global_load_lds(
        (const __attribute__((address_space(1))) unsigned int*)g,
        (__attribute__((address_space(3))) unsigned int*)l, 16, 0, 0);
}

__device__ __forceinline__ float dot4(float4 a, float4 b) {
    return a.x * b.x + a.y * b.y + a.z * b.z + a.w * b.w;
}

__device__ __forceinline__ int q4(float4 v, float s) {
    int b0 = __float2int_rn(fminf(fmaxf(v.x * s, -127.f), 127.f)) & 255;
    int b1 = __float2int_rn(fminf(fmaxf(v.y * s, -127.f), 127.f)) & 255;
    int b2 = __float2int_rn(fminf(fmaxf(v.z * s, -127.f), 127.f)) & 255;
    int b3 = __float2int_rn(fminf(fmaxf(v.w * s, -127.f), 127.f)) & 255;
    return b0 | (b1 << 8) | (b2 << 16) | (b3 << 24);
}

// One wave per row: L2-normalize, quantize to i8 (scale QS), exact fp32 diag,
// column log2-weights (0 or 1), zero row-sum accumulator.
__global__ __launch_bounds__(256) void norm_kernel(
    const float* __restrict__ A, const float* __restrict__ S,
    const int* __restrict__ labels, signed char* __restrict__ aQ,
    signed char* __restrict__ sQ, float* __restrict__ diag,
    float* __restrict__ lw2, float* __restrict__ lsum) {
    const int wave = threadIdx.x >> 6, lane = threadIdx.x & 63;
    const int row = blockIdx.x * 4 + wave;
    const float4* a4 = (const float4*)(A + (size_t)row * DIM);
    const float4* s4 = (const float4*)(S + (size_t)row * DIM);
    float4 a0 = a4[lane], a1 = a4[lane + 64];
    float4 s0 = s4[lane], s1 = s4[lane + 64];
    float saa = dot4(a0, a0) + dot4(a1, a1);
    float sss = dot4(s0, s0) + dot4(s1, s1);
    float sas = dot4(a0, s0) + dot4(a1, s1);
    for (int m = 1; m < 64; m <<= 1) {
        saa += __shfl_xor(saa, m);
        sss += __shfl_xor(sss, m);
        sas += __shfl_xor(sas, m);
    }
    const float ra = rsqrtf(saa), rs = rsqrtf(sss);
    signed char* arow = aQ + (size_t)row * DIM;
    signed char* srow = sQ + (size_t)row * DIM;
    *(int*)(arow + lane * 4)       = q4(a0, ra * QS);
    *(int*)(arow + 256 + lane * 4) = q4(a1, ra * QS);
    *(int*)(srow + lane * 4)       = q4(s0, rs * QS);
    *(int*)(srow + 256 + lane * 4) = q4(s1, rs * QS);
    if (lane == 0) {
        diag[row] = sas * ra * rs * INV_T;
        // Uniform column weighting (incl. diagonal) is exact for the final
        // loss: only label==1 rows' lse is consumed, and those rows' diagonal
        // column has log_w==0 in the reference anyway. log2-weight: 0 or 1.
        lw2[row] = (labels[row] == 0) ? 1.0f : 0.0f;
        lsum[row] = 0.0f;
    }
}

// ---------------------------------------------------------------------------
// Barrier-free fused i8 GEMM + exp2 + row-sum (v7).
// Block = 64 rows x 1024 cols; 4 waves with DISJOINT 64-col slices.
// Shared read-only A panel 64x512 (32 KB, staged once, ONE barrier total).
// Each wave stages its own 4 KB B window into a PRIVATE LDS double-buffer
// (coalesced global_load_lds) -> zero cross-wave dependencies in the main
// loop -> zero barriers; per-wave counted vmcnt(4). 64 KB LDS -> 2 blocks/CU,
// 2 independent waves/SIMD mutually hide latency.
// ---------------------------------------------------------------------------
#define BM 64

__global__ __launch_bounds__(256) void lse_gemm(
    const signed char* __restrict__ Aq, const signed char* __restrict__ Bq,
    const float* __restrict__ lw2, float* __restrict__ lsum) {
    __shared__ __align__(16) char ldsA[BM * 512];      // 32 KB shared A panel
    __shared__ __align__(16) char ldsB[4 * 2 * 4096];  // 32 KB: per-wave dbuf

    const int bid = blockIdx.x;                 // 1024 blocks
    const int rt = bid & 127, ctg = bid >> 7;   // rt-consecutive -> XCD spread
    const int row0 = rt * BM;
    const int colg = ctg * 1024;

    const int tid = threadIdx.x;
    const int wave = tid >> 6, lane = tid & 63;
    const int fr = lane & 15, grp = lane >> 4;
    const int wbase = wave << 10;

    // ---- A panel staging (r4-verified swizzle): 8 rounds x 8 rows.
    // Thread t -> dest byte r*4096 + t*16 -> row r*8+(t>>5), phys slot t&31;
    // fetch logical slot (t&31)^(row&31).
#pragma unroll
    for (int r = 0; r < 8; ++r) {
        const int rowA = r * 8 + (tid >> 5);
        const int l = (tid & 31) ^ (rowA & 31);
        gload_lds16(Aq + (size_t)(row0 + rowA) * DIM + l * 16,
                    ldsA + r * 4096 + wbase);
    }

    // ---- private B staging geometry (per wave, 4 KB window = 64 rows x 64 B)
    // load i, lane l: dest = region + i*1024 + l*16 -> row i*16+(l>>2),
    // phys slot l&3; fetch logical slot (l&3)^((l>>3)&3)  [same involution
    // family as r3/r4-verified; ((i*16+(l>>2))>>1)&3 == (l>>3)&3].
    const int brow = lane >> 2;
    const int bsl = (lane & 3) ^ ((lane >> 3) & 3);
    const signed char* Bwave =
        Bq + (size_t)(colg + wave * 64 + brow) * DIM + bsl * 16;
    char* breg = ldsB + wave * 8192;  // this wave's 2x4KB region

#define STAGE_B(buf, ct, k)                                                   \
    do {                                                                      \
        _Pragma("unroll")                                                     \
        for (int i = 0; i < 4; ++i)                                           \
            gload_lds16(Bwave + (size_t)((ct) * 256 + i * 16) * DIM + (k) * 64, \
                        breg + (buf) * 4096 + i * 1024);                      \
    } while (0)

    STAGE_B(0, 0, 0);  // first B window; in flight across the barrier

    asm volatile("s_waitcnt vmcnt(4)" ::: "memory");  // A panel staged
    asm volatile("" ::: "memory");
    __builtin_amdgcn_s_barrier();                     // the ONLY barrier
    asm volatile("" ::: "memory");

    // fragment-read swizzles (both r3/r4-verified, 0 conflicts measured)
    const int bslot = (grp ^ ((fr >> 1) & 3)) << 4;   // B: 2-way (free)

    float rsum[4][4] = {};  // [m][j] accumulated across all 4 ct
    for (int ct = 0; ct < 4; ++ct) {
        i32x4 acc[4][4] = {};
#pragma unroll
        for (int k = 0; k < 8; ++k) {
            const int w = ct * 8 + k;
            const int cur = w & 1;
            // guard: this wave's prior ds_reads complete before overwrite
            asm volatile("s_waitcnt lgkmcnt(0)" ::: "memory");
            if (w < 31) {
                const int w2 = w + 1;
                STAGE_B(cur ^ 1, w2 >> 3, w2 & 7);
                asm volatile("s_waitcnt vmcnt(4)" ::: "memory");
            } else {
                asm volatile("s_waitcnt vmcnt(0)" ::: "memory");
            }

            i32x4 a[4], b[4];
#pragma unroll
            for (int n = 0; n < 4; ++n)
                b[n] = *(const i32x4*)&breg[cur * 4096 + (n * 16 + fr) * 64 + bslot];
#pragma unroll
            for (int m = 0; m < 4; ++m) {
                const int rowm = m * 16 + fr;
                const int ps = ((k * 4 + grp) ^ (rowm & 31)) << 4;
                a[m] = *(const i32x4*)&ldsA[rowm * 512 + ps];
            }
#pragma unroll
            for (int m = 0; m < 4; ++m)
#pragma unroll
                for (int n = 0; n < 4; ++n)
                    acc[m][n] = __builtin_amdgcn_mfma_i32_16x16x64_i8(
                        a[m], b[n], acc[m][n], 0, 0, 0);
        }

        // per-ct epilogue: uniform column weights, exp2-folded dequant
        // (overlaps with the already-issued next-window stage).
        const int col0 = colg + ct * 256 + wave * 64;
        float lwv[4];
#pragma unroll
        for (int n = 0; n < 4; ++n)
            lwv[n] = lw2[col0 + n * 16 + fr];
#pragma unroll
        for (int m = 0; m < 4; ++m)
#pragma unroll
            for (int n = 0; n < 4; ++n)
#pragma unroll
                for (int j = 0; j < 4; ++j)
                    rsum[m][j] += exp2f(fmaf((float)acc[m][n][j], DEQ2, lwv[n]));
    }
#undef STAGE_B

    // final: reduce rsum over the 16-lane fr group, one atomicAdd per row
#pragma unroll
    for (int m = 0; m < 4; ++m)
#pragma unroll
        for (int j = 0; j < 4; ++j) {
            float v = rsum[m][j];
            v += __shfl_xor(v, 1);
            v += __shfl_xor(v, 2);
            v += __shfl_xor(v, 4);
            v += __shfl_xor(v, 8);
            if (fr == 0)
                atomicAdd(&lsum[row0 + m * 16 + grp * 4 + j], v);
        }
}

// 1024 threads, single block: final scalar reduction.
__global__ __launch_bounds__(1024) void finalize_kernel(
    const float* __restrict__ lsum, const float* __restrict__ diag,
    const int* __restrict__ labels, float* __restrict__ out) {
    const int tid = threadIdx.x;
    float sl = 0.f, sd = 0.f, mx = -1e9f;
    int np_ = 0, nn_ = 0;
#pragma unroll
    for (int i = tid; i < NROWS; i += 1024) {
        const float dg = diag[i];
        if (labels[i] == 1) {
            sl += logf(lsum[i]) - dg;
            sd += dg;
            np_++;
        } else {
            nn_++;
            mx = fmaxf(mx, dg);
        }
    }
    for (int m = 1; m < 64; m <<= 1) {
        sl += __shfl_xor(sl, m);
        sd += __shfl_xor(sd, m);
        mx = fmaxf(mx, __shfl_xor(mx, m));
        np_ += __shfl_xor(np_, m);
        nn_ += __shfl_xor(nn_, m);
    }
    __shared__ float rsl[16], rsd[16], rmx[16];
    __shared__ int rnp[16], rnn[16];
    const int wave = tid >> 6, lane = tid & 63;
    if (lane == 0) {
        rsl[wave] = sl; rsd[wave] = sd; rmx[wave] = mx;
        rnp[wave] = np_; rnn[wave] = nn_;
    }
    __syncthreads();
    if (tid == 0) {
        float SL = 0.f, SD = 0.f, MX = -1e9f;
        int NP = 0, NN = 0;
        for (int w = 0; w < 16; w++) {
            SL += rsl[w]; SD += rsd[w]; MX = fmaxf(MX, rmx[w]);
            NP += rnp[w]; NN += rnn[w];
        }
        const float infonce = SL / (float)NP;
        const float meanpos = SD / (float)NP;
        float pen = fmaxf(MX - meanpos + 0.2f, 0.0f);
        if (NN == 0) pen = 0.0f;
        out[0] = infonce + pen;
    }
}

extern "C" void kernel_launch(void* const* d_in, const int* in_sizes, int n_in,
                              void* d_out, int out_size, void* d_ws, size_t ws_size,
                              hipStream_t stream) {
    const float* A = (const float*)d_in[0];
    const float* S = (const float*)d_in[1];
    const int* labels = (const int*)d_in[2];
    float* out = (float*)d_out;

    char* ws = (char*)d_ws;
    signed char* aQ = (signed char*)ws;                          // 4 MB
    signed char* sQ = (signed char*)(ws + (size_t)NROWS * DIM);  // 4 MB
    char* p = ws + (size_t)NROWS * DIM * 2;
    float* diag = (float*)p;                // 32 KB
    float* lw2 = (float*)(p + 32768);       // 32 KB
    float* lsum = (float*)(p + 65536);      // 32 KB

    norm_kernel<<<NROWS / 4, 256, 0, stream>>>(A, S, labels, aQ, sQ, diag, lw2, lsum);
    lse_gemm<<<128 * 8, 256, 0, stream>>>(aQ, sQ, lw2, lsum);
    finalize_kernel<<<1, 1024, 0, stream>>>(lsum, diag, labels, out);
}